// Round 4
// baseline (253.187 us; speedup 1.0000x reference)
//
#include <hip/hip_runtime.h>
#include <cstdint>
#include <cstddef>

typedef unsigned short ushort_t;
typedef unsigned int u32;
typedef __attribute__((ext_vector_type(8))) short bf16x8;
typedef __attribute__((ext_vector_type(4))) float f32x4;
typedef __attribute__((ext_vector_type(4))) unsigned short u16x4;

#define DEV static __device__ __forceinline__

DEV ushort_t f2bf(float f) {
  u32 x = __float_as_uint(f);
  x += 0x7fff + ((x >> 16) & 1);
  return (ushort_t)(x >> 16);
}
DEV float bf2f(ushort_t u) { return __uint_as_float(((u32)u) << 16); }

DEV void gload16(const ushort_t* g, ushort_t* l) {
  __builtin_amdgcn_global_load_lds(
      (const __attribute__((address_space(1))) void*)g,
      (__attribute__((address_space(3))) void*)l, 16, 0, 0);
}

#define VMW(n) asm volatile("s_waitcnt vmcnt(" #n ")" ::: "memory")
#define LGKM0 asm volatile("s_waitcnt lgkmcnt(0)" ::: "memory")
#define BAR() __builtin_amdgcn_s_barrier()

// Dims: B=8, S=512, D=1024, H=16, DH=64, M=B*S=4096 per side.

// ---------------------------------------------------------------------------
__global__ __launch_bounds__(256) void cvt_inputs(
    const float* __restrict__ xa, const float* __restrict__ xb,
    ushort_t* __restrict__ oa, ushort_t* __restrict__ ob) {
  int i = blockIdx.x * 256 + threadIdx.x;
  f32x4 va = ((const f32x4*)xa)[i];
  f32x4 vb = ((const f32x4*)xb)[i];
  u16x4 ua, ub;
#pragma unroll
  for (int j = 0; j < 4; ++j) { ua[j] = f2bf(va[j]); ub[j] = f2bf(vb[j]); }
  ((u16x4*)oa)[i] = ua;
  ((u16x4*)ob)[i] = ub;
}

// ---------------------------------------------------------------------------
// z<8: W [K=1024][1024] f32 -> Wt [1024][1024] bf16 into WTall slot z.
// z==8: gate W [2048][1024] -> WgT [1024][2048].
// z==9,10: plain (no transpose) f32->bf16 of Wo into WoBF slot z-9.
struct Src11 { const float* p[11]; };

__global__ __launch_bounds__(256) void transpose_cvt(
    Src11 srcs, ushort_t* __restrict__ WTall, ushort_t* __restrict__ WgT,
    ushort_t* __restrict__ WoBF) {
  const int z = blockIdx.z;
  if (z != 8 && blockIdx.y >= 32) return;
  const float* src = srcs.p[z];
  int tx = threadIdx.x & 31, ty = threadIdx.x >> 5;
  int n0 = blockIdx.x << 5, k0 = blockIdx.y << 5;
  if (z >= 9) {
    ushort_t* dst = WoBF + ((size_t)(z - 9) << 20);
#pragma unroll
    for (int i = 0; i < 4; ++i) {
      size_t off = (size_t)(k0 + ty + i * 8) * 1024 + n0 + tx;
      dst[off] = f2bf(src[off]);
    }
    return;
  }
  const int K = (z == 8) ? 2048 : 1024;
  ushort_t* dst = (z == 8) ? WgT : WTall + ((size_t)z << 20);
  __shared__ float t[32][33];
#pragma unroll
  for (int i = 0; i < 4; ++i)
    t[ty + i * 8][tx] = src[(size_t)(k0 + ty + i * 8) * 1024 + n0 + tx];
  __syncthreads();
#pragma unroll
  for (int i = 0; i < 4; ++i)
    dst[(size_t)(n0 + ty + i * 8) * K + k0 + tx] = f2bf(t[tx][ty + i * 8]);
}

// ---------------------------------------------------------------------------
// gb2[dir][n] = sum_k bo_dir[k] * Wg[1024+k][n]  (= bo @ Wg_bot)
__global__ __launch_bounds__(256) void gb2_kernel(
    const float* __restrict__ bo0, const float* __restrict__ bo1,
    const ushort_t* __restrict__ WgT, float* __restrict__ gb2) {
  int idx = blockIdx.x * 256 + threadIdx.x;  // 0..2047
  int dir = idx >> 10, n = idx & 1023;
  const float* bo = dir ? bo1 : bo0;
  const ushort_t* wrow = WgT + ((size_t)n << 11) + 1024;
  float s = 0.f;
  for (int k = 0; k < 1024; ++k) s += bo[k] * bf2f(wrow[k]);
  gb2[idx] = s;
}

// ---------------------------------------------------------------------------
// WpT[g][n][j] = sum_k Wo_g[j][k] * Wg[1024+k][n]   (= (Wo_g @ Wg_bot)^T)
// A[m][k] = WgT[m&1023][1024+k], B[n][k] = WoBF[g][n][k]. M=2048, N=1024.
__global__ __launch_bounds__(256, 3) void gemm_wp(
    const ushort_t* __restrict__ WgT, const ushort_t* __restrict__ WoBF,
    ushort_t* __restrict__ WpT) {
  __shared__ ushort_t As[128 * 64];
  __shared__ ushort_t Bs[128 * 64];
  const int tid = threadIdx.x;
  const int w = tid >> 6, lane = tid & 63;
  const int g = lane >> 4, c = lane & 15;
  const int wm = (w >> 1) << 6, wn = (w & 1) << 6;
  const int m0 = blockIdx.x << 7, n0 = blockIdx.y << 7;
  const int group = m0 >> 10;
  const int csw = (lane & 7) ^ (lane >> 3);

  f32x4 acc[4][4];
#pragma unroll
  for (int i = 0; i < 4; ++i)
#pragma unroll
    for (int j = 0; j < 4; ++j) acc[i][j] = f32x4{0.f, 0.f, 0.f, 0.f};

  for (int k0 = 0; k0 < 1024; k0 += 64) {
#pragma unroll
    for (int i = 0; i < 4; ++i) {
      const int chunk = (w << 2) + i;
      const int row = (chunk << 3) + (lane >> 3);
      gload16(WgT + ((size_t)((m0 + row) & 1023) << 11) + 1024 + k0 + (csw << 3),
              &As[(size_t)chunk << 9]);
      gload16(WoBF + ((size_t)group << 20) + ((size_t)(n0 + row) << 10) + k0 + (csw << 3),
              &Bs[(size_t)chunk << 9]);
    }
    __syncthreads();
    const int cg = c & 7;
#pragma unroll
    for (int ks = 0; ks < 2; ++ks) {
      bf16x8 af[4], bfr[4];
#pragma unroll
      for (int mi = 0; mi < 4; ++mi)
        af[mi] = *(const bf16x8*)&As[((wm + mi * 16 + c) << 6) +
                                     ((((ks << 2) | g) ^ cg) << 3)];
#pragma unroll
      for (int ni = 0; ni < 4; ++ni)
        bfr[ni] = *(const bf16x8*)&Bs[((wn + ni * 16 + c) << 6) +
                                      ((((ks << 2) | g) ^ cg) << 3)];
#pragma unroll
      for (int mi = 0; mi < 4; ++mi)
#pragma unroll
        for (int ni = 0; ni < 4; ++ni)
          acc[mi][ni] = __builtin_amdgcn_mfma_f32_16x16x32_bf16(
              af[mi], bfr[ni], acc[mi][ni], 0, 0, 0);
    }
    __syncthreads();
  }
#pragma unroll
  for (int ni = 0; ni < 4; ++ni) {
    const int n = n0 + wn + ni * 16 + c;
#pragma unroll
    for (int mi = 0; mi < 4; ++mi) {
      const int mb = m0 + wm + mi * 16 + (g << 2);
      f32x4 a = acc[mi][ni];
#pragma unroll
      for (int r = 0; r < 4; ++r)
        WpT[((size_t)group << 20) + ((size_t)((mb + r) & 1023) << 10) + n] = f2bf(a[r]);
    }
  }
}

// ---------------------------------------------------------------------------
// 256x256 / BK=64 / 8-wave GEMM with per-phase counted-vmcnt pipeline.
// Stage-chunk stream per K-tile: {B0,B1,A_q0,A_q1,A_q2,A_q3} (8 loads/thread),
// issued one tile ahead; vmcnt ledger 3/4/5/6 steady, 3/2/1/0 on the tail tile.
// G_QKV: M=8192 ([Xt;Xc]), N=4096 (3 QKV slots + gate_top logits). K=1024.
// G_OG : M=8192 ([ctx0;ctx1]), N=2048 (ao | gl += ctx@W' + gb2). K=1024.
enum { G_QKV = 0, G_OG = 1 };
struct Bias8 { const float* p[8]; };

#define RD_A(Q)                                                                \
  _Pragma("unroll") for (int m2 = 0; m2 < 2; ++m2)                             \
    _Pragma("unroll") for (int kk = 0; kk < 2; ++kk)                           \
      af[m2][kk] = *(const bf16x8*)&As[buf][(((wm << 7) + (((Q)*2 + m2) << 4) + c) << 6) + \
                                           ((((kk << 2) | g) ^ c7) << 3)]
#define MM(Q)                                                                  \
  _Pragma("unroll") for (int m2 = 0; m2 < 2; ++m2)                             \
    _Pragma("unroll") for (int nf = 0; nf < 4; ++nf) {                         \
      acc[(Q)*2 + m2][nf] = __builtin_amdgcn_mfma_f32_16x16x32_bf16(           \
          af[m2][0], bfr[nf][0], acc[(Q)*2 + m2][nf], 0, 0, 0);                \
      acc[(Q)*2 + m2][nf] = __builtin_amdgcn_mfma_f32_16x16x32_bf16(           \
          af[m2][1], bfr[nf][1], acc[(Q)*2 + m2][nf], 0, 0, 0);                \
    }

#define GTILE(T_, ST_, V0_, V1_, V2_, V3_)                                     \
  do {                                                                         \
    const int buf = (T_)&1;                                                    \
    const int ko = ((T_) + 1) << 6;                                            \
    bf16x8 af[2][2];                                                           \
    VMW(V0_); BAR();                                                           \
    _Pragma("unroll") for (int nf = 0; nf < 4; ++nf)                           \
      _Pragma("unroll") for (int kk = 0; kk < 2; ++kk)                         \
        bfr[nf][kk] = *(const bf16x8*)&Bs[buf][(((wn << 6) + (nf << 4) + c) << 6) + \
                                              ((((kk << 2) | g) ^ c7) << 3)];  \
    RD_A(0);                                                                   \
    if (ST_) stageB(buf ^ 1, ko, 0);                                           \
    BAR(); LGKM0;                                                              \
    __builtin_amdgcn_s_setprio(1); MM(0); __builtin_amdgcn_s_setprio(0);       \
    VMW(V1_); BAR();                                                           \
    RD_A(1);                                                                   \
    if (ST_) stageB(buf ^ 1, ko, 1);                                           \
    BAR(); LGKM0;                                                              \
    __builtin_amdgcn_s_setprio(1); MM(1); __builtin_amdgcn_s_setprio(0);       \
    VMW(V2_); BAR();                                                           \
    RD_A(2);                                                                   \
    if (ST_) { stageA(buf ^ 1, ko, 0); stageA(buf ^ 1, ko, 1); }               \
    BAR(); LGKM0;                                                              \
    __builtin_amdgcn_s_setprio(1); MM(2); __builtin_amdgcn_s_setprio(0);       \
    VMW(V3_); BAR();                                                           \
    RD_A(3);                                                                   \
    if (ST_) { stageA(buf ^ 1, ko, 2); stageA(buf ^ 1, ko, 3); }               \
    BAR(); LGKM0;                                                              \
    __builtin_amdgcn_s_setprio(1); MM(3); __builtin_amdgcn_s_setprio(0);       \
  } while (0)

template <int MODE>
__global__ __launch_bounds__(512, 2) void gemm256(
    const ushort_t* __restrict__ Aa, const ushort_t* __restrict__ Ab,
    const ushort_t* __restrict__ WTall, const ushort_t* __restrict__ WgT,
    const ushort_t* __restrict__ WpT, Bias8 bt,
    ushort_t* __restrict__ outQ, ushort_t* __restrict__ gl) {
  __shared__ ushort_t As[2][16384];
  __shared__ ushort_t Bs[2][16384];
  const int tid = threadIdx.x;
  const int wid = tid >> 6, lane = tid & 63;
  const int g = lane >> 4, c = lane & 15, c7 = c & 7;
  const int wm = wid >> 2, wn = wid & 3;
  constexpr int NB = (MODE == G_QKV) ? 512 : 256;
  const int bid = (int)blockIdx.x;
  const int wk = (bid & 7) * (NB >> 3) + (bid >> 3);  // XCD-contiguous
  const int mt = wk & 31, nt = wk >> 5;
  const int m0 = mt << 8, n0 = nt << 8;
  const int group = m0 >> 12;
  const int nch = n0 >> 10;

  const ushort_t* Asrc = (MODE == G_QKV)
      ? (group ? Ab : Aa) + ((size_t)(m0 & 4095) << 10)
      : Aa + ((size_t)m0 << 10);

  const ushort_t* Bbase;
  int bstride, bidx = -1;
  if (MODE == G_QKV) {
    if (nch < 3) {
      bidx = group * 3 + nch;
      Bbase = WTall + ((size_t)bidx << 20) + ((size_t)(n0 & 1023) << 10);
      bstride = 1024;
    } else {
      Bbase = WgT + ((size_t)(n0 & 1023) << 11);
      bstride = 2048;
    }
  } else {
    if (nch == 0) {
      Bbase = WTall + ((size_t)(6 + group) << 20) + ((size_t)n0 << 10);
      bstride = 1024;
    } else {
      Bbase = WpT + ((size_t)group << 20) + ((size_t)(n0 & 1023) << 10);
      bstride = 1024;
    }
  }

  auto stageB = [&](int bf_, int ko, int h) {
#pragma unroll
    for (int i = 0; i < 2; ++i) {
      int rl = (i << 6) + (wid << 3) + (lane >> 3);
      int row = (h << 7) + rl;
      int cs = (lane & 7) ^ (lane >> 3);
      gload16(Bbase + (size_t)row * bstride + ko + (cs << 3),
              &Bs[bf_][(h << 13) + (i << 12) + (wid << 9)]);
    }
  };
  auto stageA = [&](int bf_, int ko, int q) {
    int rl = (wid << 3) + (lane >> 3);
    int row = (q << 5) + (rl & 31) + ((rl & 32) << 2);
    int cs = (lane & 7) ^ (lane >> 3);
    gload16(Asrc + ((size_t)row << 10) + ko + (cs << 3),
            &As[bf_][((q << 5) + ((wid & 3) << 3) + ((wid >> 2) << 7)) << 6]);
  };

  f32x4 acc[8][4];
#pragma unroll
  for (int i = 0; i < 8; ++i)
#pragma unroll
    for (int j = 0; j < 4; ++j) acc[i][j] = f32x4{0.f, 0.f, 0.f, 0.f};

  // prologue: tile 0 in stream order {B0,B1,A0..A3}
  stageB(0, 0, 0); stageB(0, 0, 1);
  stageA(0, 0, 0); stageA(0, 0, 1); stageA(0, 0, 2); stageA(0, 0, 3);

  bf16x8 bfr[4][2];
  for (int t = 0; t < 15; ++t) GTILE(t, 1, 3, 4, 5, 6);
  GTILE(15, 0, 3, 2, 1, 0);

  // Epilogue. D frag: row(M) = 4*(lane>>4)+reg, col(N) = lane&15.
  const float* bp_ = (MODE == G_QKV) ? (nch < 3 ? bt.p[bidx] : bt.p[6])
                                     : (nch == 0 ? bt.p[group] : bt.p[2 + group]);
#pragma unroll
  for (int mf = 0; mf < 8; ++mf) {
    const int mb = m0 + (wm << 7) + (mf << 4) + (g << 2);
#pragma unroll
    for (int nf = 0; nf < 4; ++nf) {
      const int n = n0 + (wn << 6) + (nf << 4) + c;
      const int nloc = n & 1023;
      const float bv = bp_[nloc];
      f32x4 a = acc[mf][nf];
      if (MODE == G_QKV) {
        if (nch < 3) {
          const int mrow = mb & 4095, b = mrow >> 9, s = mrow & 511;
          const int h = nloc >> 6, d = nloc & 63;
          ushort_t* base = outQ + ((size_t)bidx << 22);
          if (bidx == 1 || bidx == 5) {  // V^T [b][h][d][s]
            u16x4 o;
#pragma unroll
            for (int r = 0; r < 4; ++r) o[r] = f2bf(a[r] + bv);
            *(u16x4*)&base[(((size_t)((b * 16 + h) * 64 + d)) << 9) + s] = o;
          } else {  // [b][h][s][d]
#pragma unroll
            for (int r = 0; r < 4; ++r)
              base[(((size_t)((b * 16 + h) * 512 + s + r)) << 6) + d] = f2bf(a[r] + bv);
          }
        } else {  // gate_top logits (bf16)
#pragma unroll
          for (int r = 0; r < 4; ++r)
            gl[((size_t)(mb + r) << 10) + nloc] = f2bf(a[r] + bv);
        }
      } else {
        if (nch == 0) {  // ao = ctx@Wo + bo
#pragma unroll
          for (int r = 0; r < 4; ++r)
            outQ[((size_t)(mb + r) << 10) + nloc] = f2bf(a[r] + bv);
        } else {  // gl += ctx@W' + gb2
#pragma unroll
          for (int r = 0; r < 4; ++r) {
            size_t off = ((size_t)(mb + r) << 10) + nloc;
            gl[off] = f2bf(a[r] + bv + bf2f(gl[off]));
          }
        }
      }
    }
  }
}

// ---------------------------------------------------------------------------
// Fused attention, both dirs (unchanged from r3; KL row-shift dropped —
// softmax is shift-invariant per row).
__global__ __launch_bounds__(256, 2) void attn_kernel(
    const ushort_t* __restrict__ QKV, ushort_t* __restrict__ ctx) {
  __shared__ ushort_t kv[2][8192];
  const int tid = threadIdx.x, w = tid >> 6, lane = tid & 63;
  const int g = lane >> 4, c = lane & 15, c7 = c & 7;
  const int bid = (int)blockIdx.x;
  const int wid = (bid & 7) * 256 + (bid >> 3);
  const int dir = wid >> 10;
  const int bh = (wid >> 3) & 127, qt = wid & 7;
  const int q0 = (qt << 6) + (w << 4);
  const int qs = dir ? 2 : 3, ks = dir ? 4 : 0, vs = dir ? 5 : 1;
  const ushort_t* Qb = QKV + ((size_t)qs << 22) + ((size_t)bh << 15);
  const ushort_t* Kb = QKV + ((size_t)ks << 22) + ((size_t)bh << 15);
  const ushort_t* Vb = QKV + ((size_t)vs << 22) + ((size_t)bh << 15);

  auto stageK = [&](int b, int kc) {
#pragma unroll
    for (int i = 0; i < 4; ++i) {
      int idx = tid + (i << 8);
      int r = idx >> 3, sl = idx & 7;
      int cs = sl ^ (r & 7);
      gload16(Kb + (((size_t)((kc << 7) + r)) << 6) + (cs << 3), &kv[b][idx << 3]);
    }
  };
  auto stageV = [&](int b, int vc) {
#pragma unroll
    for (int i = 0; i < 4; ++i) {
      int idx = tid + (i << 8);
      int r = idx >> 4, sl = idx & 15;
      int cs = sl ^ (r & 15);
      gload16(Vb + ((size_t)r << 9) + (vc << 7) + (cs << 3), &kv[b][idx << 3]);
    }
  };

  bf16x8 qf0 = *(const bf16x8*)&Qb[((q0 + c) << 6) + (g << 3)];
  bf16x8 qf1 = *(const bf16x8*)&Qb[((q0 + c) << 6) + 32 + (g << 3)];

  f32x4 s[32];
  float mx = -1e30f;
  int buf = 0;
  stageK(0, 0);
  __syncthreads();
#pragma unroll
  for (int kc = 0; kc < 4; ++kc) {
    if (kc < 3) stageK(buf ^ 1, kc + 1);
    __builtin_amdgcn_s_setprio(1);
#pragma unroll
    for (int t = 0; t < 8; ++t) {
      const ushort_t* base = &kv[buf][((t << 4) + c) << 6];
      bf16x8 a0 = *(const bf16x8*)&base[(g ^ c7) << 3];
      bf16x8 a1 = *(const bf16x8*)&base[((4 | g) ^ c7) << 3];
      f32x4 z = {0.f, 0.f, 0.f, 0.f};
      z = __builtin_amdgcn_mfma_f32_16x16x32_bf16(a0, qf0, z, 0, 0, 0);
      z = __builtin_amdgcn_mfma_f32_16x16x32_bf16(a1, qf1, z, 0, 0, 0);
      s[kc * 8 + t] = z;
      mx = fmaxf(mx, fmaxf(fmaxf(z[0], z[1]), fmaxf(z[2], z[3])));
    }
    __builtin_amdgcn_s_setprio(0);
    __syncthreads();
    buf ^= 1;
  }
  stageV(0, 0);
  buf = 0;

  mx = fmaxf(mx, __shfl_xor(mx, 16, 64));
  mx = fmaxf(mx, __shfl_xor(mx, 32, 64));
  const float SC = 0.125f;
  float sum = 0.f;
#pragma unroll
  for (int t = 0; t < 32; ++t) {
#pragma unroll
    for (int r = 0; r < 4; ++r) {
      float p = __expf((s[t][r] - mx) * SC);
      s[t][r] = p;
      sum += p;
    }
  }
  sum += __shfl_xor(sum, 16, 64);
  sum += __shfl_xor(sum, 32, 64);
  const float inv = 1.0f / sum;

  f32x4 pacc[4];
#pragma unroll
  for (int dt = 0; dt < 4; ++dt) pacc[dt] = f32x4{0.f, 0.f, 0.f, 0.f};
  const int s1 = ((g & 1) << 5) + c;
  const int s2 = s1 + 16;
  const bool hi = (g >> 1) != 0;
  __syncthreads();
#pragma unroll
  for (int vc = 0; vc < 4; ++vc) {
    if (vc < 3) stageV(buf ^ 1, vc + 1);
#pragma unroll
    for (int t2l = 0; t2l < 4; ++t2l) {
      const int t2 = (vc << 2) + t2l;
      u32 A0 = ((u32)f2bf(s[2 * t2][1]) << 16) | f2bf(s[2 * t2][0]);
      u32 A1p = ((u32)f2bf(s[2 * t2][3]) << 16) | f2bf(s[2 * t2][2]);
      u32 B0 = ((u32)f2bf(s[2 * t2 + 1][1]) << 16) | f2bf(s[2 * t2 + 1][0]);
      u32 B1 = ((u32)f2bf(s[2 * t2 + 1][3]) << 16) | f2bf(s[2 * t2 + 1][2]);
      u32 xA0 = (u32)__shfl((int)A0, s1, 64), xA1 = (u32)__shfl((int)A1p, s1, 64);
      u32 xB0 = (u32)__shfl((int)B0, s1, 64), xB1 = (u32)__shfl((int)B1, s1, 64);
      u32 yA0 = (u32)__shfl((int)A0, s2, 64), yA1 = (u32)__shfl((int)A1p, s2, 64);
      u32 yB0 = (u32)__shfl((int)B0, s2, 64), yB1 = (u32)__shfl((int)B1, s2, 64);
      union { bf16x8 v; u32 wd[4]; } pb;
      pb.wd[0] = hi ? xB0 : xA0;
      pb.wd[1] = hi ? xB1 : xA1;
      pb.wd[2] = hi ? yB0 : yA0;
      pb.wd[3] = hi ? yB1 : yA1;
      __builtin_amdgcn_s_setprio(1);
#pragma unroll
      for (int dt = 0; dt < 4; ++dt) {
        bf16x8 av = *(const bf16x8*)
            &kv[buf][(((dt << 4) + c) << 7) + ((((t2l << 2) | g) ^ c) << 3)];
        pacc[dt] = __builtin_amdgcn_mfma_f32_16x16x32_bf16(av, pb.v, pacc[dt], 0, 0, 0);
      }
      __builtin_amdgcn_s_setprio(0);
    }
    __syncthreads();
    buf ^= 1;
  }

  const int b = bh >> 4, h = bh & 15;
  size_t obase = ((size_t)dir << 22) + ((size_t)(b * 512 + q0 + c) << 10) + (h << 6);
#pragma unroll
  for (int dt = 0; dt < 4; ++dt) {
    u16x4 o;
#pragma unroll
    for (int r = 0; r < 4; ++r) o[r] = f2bf(pacc[dt][r] * inv);
    *(u16x4*)&ctx[obase + (dt << 4) + (g << 2)] = o;
  }
}

// ---------------------------------------------------------------------------
__global__ __launch_bounds__(256) void fuse_ln(
    const float* __restrict__ xt, const float* __restrict__ xc,
    const ushort_t* __restrict__ ao, const ushort_t* __restrict__ gl,
    const float* __restrict__ lng, const float* __restrict__ lnb,
    float* __restrict__ out) {
  const int row = blockIdx.x, dir = row >> 12, r = row & 4095;
  const float* x = (dir ? xc : xt) + ((size_t)r << 10);
  const ushort_t* a = ao + ((size_t)row << 10);
  const ushort_t* glr = gl + ((size_t)row << 10);
  float* o = out + ((size_t)row << 10);
  const int t = threadIdx.x, w = t >> 6, lane = t & 63;
  f32x4 xv = ((const f32x4*)x)[t];
  u16x4 av = ((const u16x4*)a)[t];
  u16x4 gv = ((const u16x4*)glr)[t];
  f32x4 f;
  float sm = 0.f, sq = 0.f;
#pragma unroll
  for (int j = 0; j < 4; ++j) {
    float gate = 1.f / (1.f + __expf(-bf2f(gv[j])));
    float fv = gate * xv[j] + (1.f - gate) * bf2f(av[j]);
    f[j] = fv; sm += fv; sq += fv * fv;
  }
#pragma unroll
  for (int d = 1; d < 64; d <<= 1) {
    sm += __shfl_xor(sm, d, 64);
    sq += __shfl_xor(sq, d, 64);
  }
  __shared__ float ps[8];
  if (lane == 0) { ps[w] = sm; ps[4 + w] = sq; }
  __syncthreads();
  sm = ps[0] + ps[1] + ps[2] + ps[3];
  sq = ps[4] + ps[5] + ps[6] + ps[7];
  const float mu = sm * (1.f / 1024.f);
  const float var = sq * (1.f / 1024.f) - mu * mu;
  const float rstd = rsqrtf(var + 1e-5f);
  f32x4 lg = ((const f32x4*)lng)[t], lb = ((const f32x4*)lnb)[t];
  f32x4 ov;
#pragma unroll
  for (int j = 0; j < 4; ++j) ov[j] = lg[j] * (f[j] - mu) * rstd + lb[j];
  ((f32x4*)o)[t] = ov;
}

// ---------------------------------------------------------------------------
extern "C" void kernel_launch(void* const* d_in, const int* in_sizes, int n_in,
                              void* d_out, int out_size, void* d_ws, size_t ws_size,
                              hipStream_t stream) {
  (void)in_sizes; (void)n_in; (void)out_size; (void)ws_size;
  const float* title = (const float*)d_in[0];
  const float* content = (const float*)d_in[1];

  char* ws = (char*)d_ws;
  const size_t MB = 1u << 20;
  ushort_t* Xt    = (ushort_t*)(ws + 0 * MB);    // 8 MB bf16 [4096][1024]
  ushort_t* Xc    = (ushort_t*)(ws + 8 * MB);    // 8 MB
  ushort_t* ctx   = (ushort_t*)(ws + 0 * MB);    // 16 MB, reuses X after QKVG
  ushort_t* WTall = (ushort_t*)(ws + 16 * MB);   // 16 MB: 8 slots [1024][1024]
  ushort_t* WgT   = (ushort_t*)(ws + 32 * MB);   // 4 MB [1024][2048]
  ushort_t* QKV   = (ushort_t*)(ws + 36 * MB);   // 48 MB: 6 slots of 8 MB
  ushort_t* ao    = (ushort_t*)(ws + 36 * MB);   // 16 MB, reuses QKV slots 0-1
  ushort_t* gl    = (ushort_t*)(ws + 84 * MB);   // 16 MB bf16 [8192][1024]
  ushort_t* WoBF  = (ushort_t*)(ws + 100 * MB);  // 4 MB: 2 slots [1024][1024]
  ushort_t* WpT   = (ushort_t*)(ws + 104 * MB);  // 4 MB: 2 slots [1024][1024]
  float*    gb2   = (float*)   (ws + 108 * MB);  // 8 KB [2][1024]

  cvt_inputs<<<4096, 256, 0, stream>>>(title, content, Xt, Xc);

  // slots: {t2c_wk,t2c_wv,c2t_wq, t2c_wq,c2t_wk,c2t_wv, t2c_wo,c2t_wo}, gate, Wo plain x2
  Src11 srcs;
  srcs.p[0] = (const float*)d_in[4];  srcs.p[1] = (const float*)d_in[6];
  srcs.p[2] = (const float*)d_in[10]; srcs.p[3] = (const float*)d_in[2];
  srcs.p[4] = (const float*)d_in[12]; srcs.p[5] = (const float*)d_in[14];
  srcs.p[6] = (const float*)d_in[8];  srcs.p[7] = (const float*)d_in[16];
  srcs.p[8] = (const float*)d_in[18];
  srcs.p[9] = (const float*)d_in[8];  srcs.p[10] = (const float*)d_in[16];
  transpose_cvt<<<dim3(32, 64, 11), 256, 0, stream>>>(srcs, WTall, WgT, WoBF);

  gb2_kernel<<<8, 256, 0, stream>>>((const float*)d_in[9], (const float*)d_in[17],
                                    WgT, gb2);
  gemm_wp<<<dim3(16, 8), 256, 0, stream>>>(WgT, WoBF, WpT);

  Bias8 bq;
  bq.p[0] = (const float*)d_in[5];  bq.p[1] = (const float*)d_in[7];
  bq.p[2] = (const float*)d_in[11]; bq.p[3] = (const float*)d_in[3];
  bq.p[4] = (const float*)d_in[13]; bq.p[5] = (const float*)d_in[15];
  bq.p[6] = (const float*)d_in[19]; bq.p[7] = nullptr;
  gemm256<G_QKV><<<512, 512, 0, stream>>>(Xt, Xc, WTall, WgT, WpT, bq, QKV, gl);

  attn_kernel<<<2048, 256, 0, stream>>>(QKV, ctx);

  Bias8 bo;
  bo.p[0] = (const float*)d_in[9]; bo.p[1] = (const float*)d_in[17];
  bo.p[2] = gb2; bo.p[3] = gb2 + 1024;
  for (int i = 4; i < 8; ++i) bo.p[i] = nullptr;
  gemm256<G_OG><<<256, 512, 0, stream>>>(ctx, nullptr, WTall, WgT, WpT, bo, ao, gl);

  fuse_ln<<<8192, 256, 0, stream>>>(title, content, ao, gl,
                                    (const float*)d_in[20], (const float*)d_in[21],
                                    (float*)d_out);
}

// Round 5
// 226.431 us; speedup vs baseline: 1.1182x; 1.1182x over previous
//
#include <hip/hip_runtime.h>
#include <cstdint>
#include <cstddef>

typedef unsigned short ushort_t;
typedef unsigned int u32;
typedef __attribute__((ext_vector_type(8))) short bf16x8;
typedef __attribute__((ext_vector_type(4))) float f32x4;
typedef __attribute__((ext_vector_type(4))) unsigned short u16x4;

#define DEV static __device__ __forceinline__

DEV ushort_t f2bf(float f) {
  u32 x = __float_as_uint(f);
  x += 0x7fff + ((x >> 16) & 1);
  return (ushort_t)(x >> 16);
}
DEV float bf2f(ushort_t u) { return __uint_as_float(((u32)u) << 16); }

DEV void gload16(const ushort_t* g, ushort_t* l) {
  __builtin_amdgcn_global_load_lds(
      (const __attribute__((address_space(1))) void*)g,
      (__attribute__((address_space(3))) void*)l, 16, 0, 0);
}

// Dims: B=8, S=512, D=1024, H=16, DH=64, M=B*S=4096 per side.

// ---------------------------------------------------------------------------
__global__ __launch_bounds__(256) void cvt_inputs(
    const float* __restrict__ xa, const float* __restrict__ xb,
    ushort_t* __restrict__ oa, ushort_t* __restrict__ ob) {
  int i = blockIdx.x * 256 + threadIdx.x;
  f32x4 va = ((const f32x4*)xa)[i];
  f32x4 vb = ((const f32x4*)xb)[i];
  u16x4 ua, ub;
#pragma unroll
  for (int j = 0; j < 4; ++j) { ua[j] = f2bf(va[j]); ub[j] = f2bf(vb[j]); }
  ((u16x4*)oa)[i] = ua;
  ((u16x4*)ob)[i] = ub;
}

// ---------------------------------------------------------------------------
// z<8: W [K=1024][1024] f32 -> Wt [1024][1024] bf16 into WTall slot z.
// z==8: gate W [2048][1024] -> WgT [1024][2048].
// z==9,10: plain (no transpose) f32->bf16 of Wo into WoBF slot z-9.
struct Src11 { const float* p[11]; };

__global__ __launch_bounds__(256) void transpose_cvt(
    Src11 srcs, ushort_t* __restrict__ WTall, ushort_t* __restrict__ WgT,
    ushort_t* __restrict__ WoBF) {
  const int z = blockIdx.z;
  if (z != 8 && blockIdx.y >= 32) return;
  const float* src = srcs.p[z];
  int tx = threadIdx.x & 31, ty = threadIdx.x >> 5;
  int n0 = blockIdx.x << 5, k0 = blockIdx.y << 5;
  if (z >= 9) {
    ushort_t* dst = WoBF + ((size_t)(z - 9) << 20);
#pragma unroll
    for (int i = 0; i < 4; ++i) {
      size_t off = (size_t)(k0 + ty + i * 8) * 1024 + n0 + tx;
      dst[off] = f2bf(src[off]);
    }
    return;
  }
  const int K = (z == 8) ? 2048 : 1024;
  ushort_t* dst = (z == 8) ? WgT : WTall + ((size_t)z << 20);
  __shared__ float t[32][33];
#pragma unroll
  for (int i = 0; i < 4; ++i)
    t[ty + i * 8][tx] = src[(size_t)(k0 + ty + i * 8) * 1024 + n0 + tx];
  __syncthreads();
#pragma unroll
  for (int i = 0; i < 4; ++i)
    dst[(size_t)(n0 + ty + i * 8) * K + k0 + tx] = f2bf(t[tx][ty + i * 8]);
}

// ---------------------------------------------------------------------------
// gb2[dir][n] = sum_k bo_dir[k] * Wg[1024+k][n]  (= bo @ Wg_bot).
// One wave per (dir, n): lane handles 16 k's, then butterfly-reduce.
__global__ __launch_bounds__(256) void gb2_kernel(
    const float* __restrict__ bo0, const float* __restrict__ bo1,
    const ushort_t* __restrict__ WgT, float* __restrict__ gb2) {
  const int wgl = blockIdx.x * 4 + (threadIdx.x >> 6);  // 0..2047
  const int lane = threadIdx.x & 63;
  const int dir = wgl >> 10, n = wgl & 1023;
  const float* bo = dir ? bo1 : bo0;
  const ushort_t* wrow = WgT + ((size_t)n << 11) + 1024 + (lane << 4);
  float s = 0.f;
#pragma unroll
  for (int j = 0; j < 16; ++j) s += bo[(lane << 4) + j] * bf2f(wrow[j]);
#pragma unroll
  for (int d = 1; d < 64; d <<= 1) s += __shfl_xor(s, d, 64);
  if (lane == 0) gb2[wgl] = s;
}

// ---------------------------------------------------------------------------
// WpT[g][n][j] = sum_k Wo_g[j][k] * Wg[1024+k][n]   (= (Wo_g @ Wg_bot)^T)
__global__ __launch_bounds__(256, 3) void gemm_wp(
    const ushort_t* __restrict__ WgT, const ushort_t* __restrict__ WoBF,
    ushort_t* __restrict__ WpT) {
  __shared__ ushort_t As[128 * 64];
  __shared__ ushort_t Bs[128 * 64];
  const int tid = threadIdx.x;
  const int w = tid >> 6, lane = tid & 63;
  const int g = lane >> 4, c = lane & 15;
  const int wm = (w >> 1) << 6, wn = (w & 1) << 6;
  const int m0 = blockIdx.x << 7, n0 = blockIdx.y << 7;
  const int group = m0 >> 10;
  const int csw = (lane & 7) ^ (lane >> 3);

  f32x4 acc[4][4];
#pragma unroll
  for (int i = 0; i < 4; ++i)
#pragma unroll
    for (int j = 0; j < 4; ++j) acc[i][j] = f32x4{0.f, 0.f, 0.f, 0.f};

  for (int k0 = 0; k0 < 1024; k0 += 64) {
#pragma unroll
    for (int i = 0; i < 4; ++i) {
      const int chunk = (w << 2) + i;
      const int row = (chunk << 3) + (lane >> 3);
      gload16(WgT + ((size_t)((m0 + row) & 1023) << 11) + 1024 + k0 + (csw << 3),
              &As[(size_t)chunk << 9]);
      gload16(WoBF + ((size_t)group << 20) + ((size_t)(n0 + row) << 10) + k0 + (csw << 3),
              &Bs[(size_t)chunk << 9]);
    }
    __syncthreads();
    const int cg = c & 7;
#pragma unroll
    for (int ks = 0; ks < 2; ++ks) {
      bf16x8 af[4], bfr[4];
#pragma unroll
      for (int mi = 0; mi < 4; ++mi)
        af[mi] = *(const bf16x8*)&As[((wm + mi * 16 + c) << 6) +
                                     ((((ks << 2) | g) ^ cg) << 3)];
#pragma unroll
      for (int ni = 0; ni < 4; ++ni)
        bfr[ni] = *(const bf16x8*)&Bs[((wn + ni * 16 + c) << 6) +
                                      ((((ks << 2) | g) ^ cg) << 3)];
#pragma unroll
      for (int mi = 0; mi < 4; ++mi)
#pragma unroll
        for (int ni = 0; ni < 4; ++ni)
          acc[mi][ni] = __builtin_amdgcn_mfma_f32_16x16x32_bf16(
              af[mi], bfr[ni], acc[mi][ni], 0, 0, 0);
    }
    __syncthreads();
  }
#pragma unroll
  for (int ni = 0; ni < 4; ++ni) {
    const int n = n0 + wn + ni * 16 + c;
#pragma unroll
    for (int mi = 0; mi < 4; ++mi) {
      const int mb = m0 + wm + mi * 16 + (g << 2);
      f32x4 a = acc[mi][ni];
#pragma unroll
      for (int r = 0; r < 4; ++r)
        WpT[((size_t)group << 20) + ((size_t)((mb + r) & 1023) << 10) + n] = f2bf(a[r]);
    }
  }
}

// ---------------------------------------------------------------------------
// 128x128 / BK=64 / 4-wave GEMM (the proven 678 TF engine, 3 blocks/CU).
// XCD mapping: xcd = bid&7, mt = xcd*8 + (idx&7), nt = idx>>3 -> each XCD's
// A-panel is 2 MB (L2-resident), B streams once per XCD.
// M_QKVG: M=8192 ([Xt;Xc]), N=4096 = 3 QKV slots + gate-top logits. K=1024.
//         gate-top bias = gate_b + gb2 (folded); gt is pure streaming store.
// M_OG  : M=8192 ([ctx0;ctx1]), N=2048 = (ao = ctx@Wo + bo | gpart = ctx@W').
enum { M_QKVG = 0, M_OG = 1 };
struct Bias8 { const float* p[8]; };

template <int MODE>
__global__ __launch_bounds__(256, 3) void gemm_kernel(
    const ushort_t* __restrict__ Aa, const ushort_t* __restrict__ Ab,
    const ushort_t* __restrict__ WTall, const ushort_t* __restrict__ WgT,
    const ushort_t* __restrict__ WpT, Bias8 bt, const float* __restrict__ gb2,
    ushort_t* __restrict__ outQ, ushort_t* __restrict__ gt) {
  __shared__ ushort_t As[128 * 64];
  __shared__ ushort_t Bs[128 * 64];
  const int tid = threadIdx.x;
  const int w = tid >> 6, lane = tid & 63;
  const int g = lane >> 4, c = lane & 15;
  const int wm = (w >> 1) << 6, wn = (w & 1) << 6;
  const int bid = (int)blockIdx.x;
  const int xcd = bid & 7, idx = bid >> 3;
  const int mt = (xcd << 3) + (idx & 7), nt = idx >> 3;
  const int m0 = mt << 7, n0 = nt << 7;
  const int group = m0 >> 12;
  const int nch = n0 >> 10;
  const int csw = (lane & 7) ^ (lane >> 3);

  const ushort_t* Asrc = (MODE == M_QKVG)
      ? ((group ? Ab : Aa) + ((size_t)(m0 & 4095) << 10))
      : (Aa + ((size_t)m0 << 10));

  const ushort_t* Bb;
  int bstr, bidx = -1;
  if (MODE == M_QKVG) {
    if (nch < 3) {
      bidx = group * 3 + nch;
      Bb = WTall + ((size_t)bidx << 20) + ((size_t)(n0 & 1023) << 10);
      bstr = 1024;
    } else {
      Bb = WgT + ((size_t)(n0 & 1023) << 11);
      bstr = 2048;
    }
  } else {
    if (nch == 0) {
      Bb = WTall + ((size_t)(6 + group) << 20) + ((size_t)n0 << 10);
      bstr = 1024;
    } else {
      Bb = WpT + ((size_t)group << 20) + ((size_t)(n0 & 1023) << 10);
      bstr = 1024;
    }
  }

  f32x4 acc[4][4];
#pragma unroll
  for (int i = 0; i < 4; ++i)
#pragma unroll
    for (int j = 0; j < 4; ++j) acc[i][j] = f32x4{0.f, 0.f, 0.f, 0.f};

  for (int k0 = 0; k0 < 1024; k0 += 64) {
#pragma unroll
    for (int i = 0; i < 4; ++i) {
      const int chunk = (w << 2) + i;
      const int row = (chunk << 3) + (lane >> 3);
      gload16(Asrc + ((size_t)row << 10) + k0 + (csw << 3), &As[(size_t)chunk << 9]);
      gload16(Bb + (size_t)row * bstr + k0 + (csw << 3), &Bs[(size_t)chunk << 9]);
    }
    __syncthreads();
    const int cg = c & 7;
#pragma unroll
    for (int ks = 0; ks < 2; ++ks) {
      bf16x8 af[4], bfr[4];
#pragma unroll
      for (int mi = 0; mi < 4; ++mi)
        af[mi] = *(const bf16x8*)&As[((wm + mi * 16 + c) << 6) +
                                     ((((ks << 2) | g) ^ cg) << 3)];
#pragma unroll
      for (int ni = 0; ni < 4; ++ni)
        bfr[ni] = *(const bf16x8*)&Bs[((wn + ni * 16 + c) << 6) +
                                      ((((ks << 2) | g) ^ cg) << 3)];
#pragma unroll
      for (int mi = 0; mi < 4; ++mi)
#pragma unroll
        for (int ni = 0; ni < 4; ++ni)
          acc[mi][ni] = __builtin_amdgcn_mfma_f32_16x16x32_bf16(
              af[mi], bfr[ni], acc[mi][ni], 0, 0, 0);
    }
    __syncthreads();
  }

  // Epilogue. D frag: row(M) = 4*(lane>>4)+reg, col(N) = lane&15.
#pragma unroll
  for (int ni = 0; ni < 4; ++ni) {
    const int n = n0 + wn + ni * 16 + c;
    const int nloc = n & 1023;
    float bv;
    if (MODE == M_QKVG)
      bv = (nch < 3) ? bt.p[bidx][nloc]
                     : bt.p[6][nloc] + gb2[(group << 10) + nloc];
    else
      bv = (nch == 0) ? bt.p[group][nloc] : 0.f;
#pragma unroll
    for (int mi = 0; mi < 4; ++mi) {
      const int mb = m0 + wm + mi * 16 + (g << 2);
      f32x4 a = acc[mi][ni];
      if (MODE == M_QKVG) {
        if (nch < 3) {
          const int mrow = mb & 4095, b = mrow >> 9, s = mrow & 511;
          const int h = nloc >> 6, d = nloc & 63;
          ushort_t* base = outQ + ((size_t)bidx << 22);
          if (bidx == 1 || bidx == 5) {  // V^T [b][h][d][s]
            u16x4 o;
#pragma unroll
            for (int r = 0; r < 4; ++r) o[r] = f2bf(a[r] + bv);
            *(u16x4*)&base[(((size_t)((b * 16 + h) * 64 + d)) << 9) + s] = o;
          } else {  // [b][h][s][d]
#pragma unroll
            for (int r = 0; r < 4; ++r)
              base[(((size_t)((b * 16 + h) * 512 + s + r)) << 6) + d] = f2bf(a[r] + bv);
          }
        } else {  // gt = X @ Wg_top + gate_b + gb2
#pragma unroll
          for (int r = 0; r < 4; ++r)
            gt[((size_t)(mb + r) << 10) + nloc] = f2bf(a[r] + bv);
        }
      } else {
        if (nch == 0) {  // ao = ctx @ Wo + bo
#pragma unroll
          for (int r = 0; r < 4; ++r)
            outQ[((size_t)(mb + r) << 10) + nloc] = f2bf(a[r] + bv);
        } else {  // gpart = ctx @ W'
#pragma unroll
          for (int r = 0; r < 4; ++r)
            gt[((size_t)(mb + r) << 10) + nloc] = f2bf(a[r]);
        }
      }
    }
  }
}

// ---------------------------------------------------------------------------
// Fused attention, both dirs (verified r3/r4; KL row-shift dropped —
// softmax is shift-invariant per row).
__global__ __launch_bounds__(256, 2) void attn_kernel(
    const ushort_t* __restrict__ QKV, ushort_t* __restrict__ ctx) {
  __shared__ ushort_t kv[2][8192];
  const int tid = threadIdx.x, w = tid >> 6, lane = tid & 63;
  const int g = lane >> 4, c = lane & 15, c7 = c & 7;
  const int bid = (int)blockIdx.x;
  const int wid = (bid & 7) * 256 + (bid >> 3);
  const int dir = wid >> 10;
  const int bh = (wid >> 3) & 127, qt = wid & 7;
  const int q0 = (qt << 6) + (w << 4);
  const int qs = dir ? 2 : 3, ks = dir ? 4 : 0, vs = dir ? 5 : 1;
  const ushort_t* Qb = QKV + ((size_t)qs << 22) + ((size_t)bh << 15);
  const ushort_t* Kb = QKV + ((size_t)ks << 22) + ((size_t)bh << 15);
  const ushort_t* Vb = QKV + ((size_t)vs << 22) + ((size_t)bh << 15);

  auto stageK = [&](int b, int kc) {
#pragma unroll
    for (int i = 0; i < 4; ++i) {
      int idx = tid + (i << 8);
      int r = idx >> 3, sl = idx & 7;
      int cs = sl ^ (r & 7);
      gload16(Kb + (((size_t)((kc << 7) + r)) << 6) + (cs << 3), &kv[b][idx << 3]);
    }
  };
  auto stageV = [&](int b, int vc) {
#pragma unroll
    for (int i = 0; i < 4; ++i) {
      int idx = tid + (i << 8);
      int r = idx >> 4, sl = idx & 15;
      int cs = sl ^ (r & 15);
      gload16(Vb + ((size_t)r << 9) + (vc << 7) + (cs << 3), &kv[b][idx << 3]);
    }
  };

  bf16x8 qf0 = *(const bf16x8*)&Qb[((q0 + c) << 6) + (g << 3)];
  bf16x8 qf1 = *(const bf16x8*)&Qb[((q0 + c) << 6) + 32 + (g << 3)];

  f32x4 s[32];
  float mx = -1e30f;
  int buf = 0;
  stageK(0, 0);
  __syncthreads();
#pragma unroll
  for (int kc = 0; kc < 4; ++kc) {
    if (kc < 3) stageK(buf ^ 1, kc + 1);
    __builtin_amdgcn_s_setprio(1);
#pragma unroll
    for (int t = 0; t < 8; ++t) {
      const ushort_t* base = &kv[buf][((t << 4) + c) << 6];
      bf16x8 a0 = *(const bf16x8*)&base[(g ^ c7) << 3];
      bf16x8 a1 = *(const bf16x8*)&base[((4 | g) ^ c7) << 3];
      f32x4 z = {0.f, 0.f, 0.f, 0.f};
      z = __builtin_amdgcn_mfma_f32_16x16x32_bf16(a0, qf0, z, 0, 0, 0);
      z = __builtin_amdgcn_mfma_f32_16x16x32_bf16(a1, qf1, z, 0, 0, 0);
      s[kc * 8 + t] = z;
      mx = fmaxf(mx, fmaxf(fmaxf(z[0], z[1]), fmaxf(z[2], z[3])));
    }
    __builtin_amdgcn_s_setprio(0);
    __syncthreads();
    buf ^= 1;
  }
  stageV(0, 0);
  buf = 0;

  mx = fmaxf(mx, __shfl_xor(mx, 16, 64));
  mx = fmaxf(mx, __shfl_xor(mx, 32, 64));
  const float SC = 0.125f;
  float sum = 0.f;
#pragma unroll
  for (int t = 0; t < 32; ++t) {
#pragma unroll
    for (int r = 0; r < 4; ++r) {
      float p = __expf((s[t][r] - mx) * SC);
      s[t][r] = p;
      sum += p;
    }
  }
  sum += __shfl_xor(sum, 16, 64);
  sum += __shfl_xor(sum, 32, 64);
  const float inv = 1.0f / sum;

  f32x4 pacc[4];
#pragma unroll
  for (int dt = 0; dt < 4; ++dt) pacc[dt] = f32x4{0.f, 0.f, 0.f, 0.f};
  const int s1 = ((g & 1) << 5) + c;
  const int s2 = s1 + 16;
  const bool hi = (g >> 1) != 0;
  __syncthreads();
#pragma unroll
  for (int vc = 0; vc < 4; ++vc) {
    if (vc < 3) stageV(buf ^ 1, vc + 1);
#pragma unroll
    for (int t2l = 0; t2l < 4; ++t2l) {
      const int t2 = (vc << 2) + t2l;
      u32 A0 = ((u32)f2bf(s[2 * t2][1]) << 16) | f2bf(s[2 * t2][0]);
      u32 A1p = ((u32)f2bf(s[2 * t2][3]) << 16) | f2bf(s[2 * t2][2]);
      u32 B0 = ((u32)f2bf(s[2 * t2 + 1][1]) << 16) | f2bf(s[2 * t2 + 1][0]);
      u32 B1 = ((u32)f2bf(s[2 * t2 + 1][3]) << 16) | f2bf(s[2 * t2 + 1][2]);
      u32 xA0 = (u32)__shfl((int)A0, s1, 64), xA1 = (u32)__shfl((int)A1p, s1, 64);
      u32 xB0 = (u32)__shfl((int)B0, s1, 64), xB1 = (u32)__shfl((int)B1, s1, 64);
      u32 yA0 = (u32)__shfl((int)A0, s2, 64), yA1 = (u32)__shfl((int)A1p, s2, 64);
      u32 yB0 = (u32)__shfl((int)B0, s2, 64), yB1 = (u32)__shfl((int)B1, s2, 64);
      union { bf16x8 v; u32 wd[4]; } pb;
      pb.wd[0] = hi ? xB0 : xA0;
      pb.wd[1] = hi ? xB1 : xA1;
      pb.wd[2] = hi ? yB0 : yA0;
      pb.wd[3] = hi ? yB1 : yA1;
      __builtin_amdgcn_s_setprio(1);
#pragma unroll
      for (int dt = 0; dt < 4; ++dt) {
        bf16x8 av = *(const bf16x8*)
            &kv[buf][(((dt << 4) + c) << 7) + ((((t2l << 2) | g) ^ c) << 3)];
        pacc[dt] = __builtin_amdgcn_mfma_f32_16x16x32_bf16(av, pb.v, pacc[dt], 0, 0, 0);
      }
      __builtin_amdgcn_s_setprio(0);
    }
    __syncthreads();
    buf ^= 1;
  }

  const int b = bh >> 4, h = bh & 15;
  size_t obase = ((size_t)dir << 22) + ((size_t)(b * 512 + q0 + c) << 10) + (h << 6);
#pragma unroll
  for (int dt = 0; dt < 4; ++dt) {
    u16x4 o;
#pragma unroll
    for (int r = 0; r < 4; ++r) o[r] = f2bf(pacc[dt][r] * inv);
    *(u16x4*)&ctx[obase + (dt << 4) + (g << 2)] = o;
  }
}

// ---------------------------------------------------------------------------
// gate = sigmoid(gt + gpart); f = gate*x + (1-gate)*ao; out = LayerNorm(f)
__global__ __launch_bounds__(256) void fuse_ln(
    const float* __restrict__ xt, const float* __restrict__ xc,
    const ushort_t* __restrict__ ao, const ushort_t* __restrict__ gt,
    const ushort_t* __restrict__ gp,
    const float* __restrict__ lng, const float* __restrict__ lnb,
    float* __restrict__ out) {
  const int row = blockIdx.x, dir = row >> 12, r = row & 4095;
  const float* x = (dir ? xc : xt) + ((size_t)r << 10);
  const ushort_t* a = ao + ((size_t)row << 10);
  const ushort_t* g1 = gt + ((size_t)row << 10);
  const ushort_t* g2 = gp + ((size_t)row << 10);
  float* o = out + ((size_t)row << 10);
  const int t = threadIdx.x, w = t >> 6, lane = t & 63;
  f32x4 xv = ((const f32x4*)x)[t];
  u16x4 av = ((const u16x4*)a)[t];
  u16x4 gv = ((const u16x4*)g1)[t];
  u16x4 pv = ((const u16x4*)g2)[t];
  f32x4 f;
  float sm = 0.f, sq = 0.f;
#pragma unroll
  for (int j = 0; j < 4; ++j) {
    float gate = 1.f / (1.f + __expf(-(bf2f(gv[j]) + bf2f(pv[j]))));
    float fv = gate * xv[j] + (1.f - gate) * bf2f(av[j]);
    f[j] = fv; sm += fv; sq += fv * fv;
  }
#pragma unroll
  for (int d = 1; d < 64; d <<= 1) {
    sm += __shfl_xor(sm, d, 64);
    sq += __shfl_xor(sq, d, 64);
  }
  __shared__ float ps[8];
  if (lane == 0) { ps[w] = sm; ps[4 + w] = sq; }
  __syncthreads();
  sm = ps[0] + ps[1] + ps[2] + ps[3];
  sq = ps[4] + ps[5] + ps[6] + ps[7];
  const float mu = sm * (1.f / 1024.f);
  const float var = sq * (1.f / 1024.f) - mu * mu;
  const float rstd = rsqrtf(var + 1e-5f);
  f32x4 lg = ((const f32x4*)lng)[t], lb = ((const f32x4*)lnb)[t];
  f32x4 ov;
#pragma unroll
  for (int j = 0; j < 4; ++j) ov[j] = lg[j] * (f[j] - mu) * rstd + lb[j];
  ((f32x4*)o)[t] = ov;
}

// ---------------------------------------------------------------------------
extern "C" void kernel_launch(void* const* d_in, const int* in_sizes, int n_in,
                              void* d_out, int out_size, void* d_ws, size_t ws_size,
                              hipStream_t stream) {
  (void)in_sizes; (void)n_in; (void)out_size; (void)ws_size;
  const float* title = (const float*)d_in[0];
  const float* content = (const float*)d_in[1];

  char* ws = (char*)d_ws;
  const size_t MB = 1u << 20;
  ushort_t* Xt    = (ushort_t*)(ws + 0 * MB);    // 8 MB bf16 [4096][1024]
  ushort_t* Xc    = (ushort_t*)(ws + 8 * MB);    // 8 MB
  ushort_t* ctx   = (ushort_t*)(ws + 0 * MB);    // 16 MB (X dead after QKVG)
  ushort_t* WTall = (ushort_t*)(ws + 16 * MB);   // 16 MB: 8 slots [1024][1024]
  ushort_t* WgT   = (ushort_t*)(ws + 32 * MB);   // 4 MB [1024][2048]
  ushort_t* QKV   = (ushort_t*)(ws + 36 * MB);   // 48 MB: 6 slots of 8 MB
  ushort_t* ao    = (ushort_t*)(ws + 36 * MB);   // 16 MB (QKV slots 0-1, dead post-attn)
  ushort_t* gpart = (ushort_t*)(ws + 52 * MB);   // 16 MB (QKV slots 2-3, dead post-attn)
  ushort_t* gt    = (ushort_t*)(ws + 84 * MB);   // 16 MB bf16 [8192][1024]
  ushort_t* WoBF  = (ushort_t*)(ws + 100 * MB);  // 4 MB: 2 slots [1024][1024]
  ushort_t* WpT   = (ushort_t*)(ws + 104 * MB);  // 4 MB: 2 slots [1024][1024]
  float*    gb2   = (float*)   (ws + 108 * MB);  // 8 KB [2][1024]

  cvt_inputs<<<4096, 256, 0, stream>>>(title, content, Xt, Xc);

  // slots: {t2c_wk,t2c_wv,c2t_wq, t2c_wq,c2t_wk,c2t_wv, t2c_wo,c2t_wo}, gate, Wo x2
  Src11 srcs;
  srcs.p[0] = (const float*)d_in[4];  srcs.p[1] = (const float*)d_in[6];
  srcs.p[2] = (const float*)d_in[10]; srcs.p[3] = (const float*)d_in[2];
  srcs.p[4] = (const float*)d_in[12]; srcs.p[5] = (const float*)d_in[14];
  srcs.p[6] = (const float*)d_in[8];  srcs.p[7] = (const float*)d_in[16];
  srcs.p[8] = (const float*)d_in[18];
  srcs.p[9] = (const float*)d_in[8];  srcs.p[10] = (const float*)d_in[16];
  transpose_cvt<<<dim3(32, 64, 11), 256, 0, stream>>>(srcs, WTall, WgT, WoBF);

  gb2_kernel<<<512, 256, 0, stream>>>((const float*)d_in[9], (const float*)d_in[17],
                                      WgT, gb2);
  gemm_wp<<<dim3(16, 8), 256, 0, stream>>>(WgT, WoBF, WpT);

  Bias8 bq;
  bq.p[0] = (const float*)d_in[5];  bq.p[1] = (const float*)d_in[7];
  bq.p[2] = (const float*)d_in[11]; bq.p[3] = (const float*)d_in[3];
  bq.p[4] = (const float*)d_in[13]; bq.p[5] = (const float*)d_in[15];
  bq.p[6] = (const float*)d_in[19]; bq.p[7] = nullptr;
  gemm_kernel<M_QKVG><<<2048, 256, 0, stream>>>(Xt, Xc, WTall, WgT, WpT, bq, gb2,
                                                QKV, gt);

  attn_kernel<<<2048, 256, 0, stream>>>(QKV, ctx);

  Bias8 bo;
  bo.p[0] = (const float*)d_in[9]; bo.p[1] = (const float*)d_in[17];
  for (int i = 2; i < 8; ++i) bo.p[i] = nullptr;
  gemm_kernel<M_OG><<<1024, 256, 0, stream>>>(ctx, nullptr, WTall, WgT, WpT, bo, gb2,
                                              ao, gpart);

  fuse_ln<<<8192, 256, 0, stream>>>(title, content, ao, gt, gpart,
                                    (const float*)d_in[20], (const float*)d_in[21],
                                    (float*)d_out);
}

// Round 6
// 224.338 us; speedup vs baseline: 1.1286x; 1.0093x over previous
//
#include <hip/hip_runtime.h>
#include <cstdint>
#include <cstddef>

typedef unsigned short ushort_t;
typedef unsigned int u32;
typedef __attribute__((ext_vector_type(8))) short bf16x8;
typedef __attribute__((ext_vector_type(4))) float f32x4;
typedef __attribute__((ext_vector_type(4))) unsigned short u16x4;

#define DEV static __device__ __forceinline__

DEV ushort_t f2bf(float f) {
  u32 x = __float_as_uint(f);
  x += 0x7fff + ((x >> 16) & 1);
  return (ushort_t)(x >> 16);
}
DEV float bf2f(ushort_t u) { return __uint_as_float(((u32)u) << 16); }

DEV void gload16(const ushort_t* g, ushort_t* l) {
  __builtin_amdgcn_global_load_lds(
      (const __attribute__((address_space(1))) void*)g,
      (__attribute__((address_space(3))) void*)l, 16, 0, 0);
}

// Dims: B=8, S=512, D=1024, H=16, DH=64, M=B*S=4096 per side.

// ---------------------------------------------------------------------------
__global__ __launch_bounds__(256) void cvt_inputs(
    const float* __restrict__ xa, const float* __restrict__ xb,
    ushort_t* __restrict__ oa, ushort_t* __restrict__ ob) {
  int i = blockIdx.x * 256 + threadIdx.x;
  f32x4 va = ((const f32x4*)xa)[i];
  f32x4 vb = ((const f32x4*)xb)[i];
  u16x4 ua, ub;
#pragma unroll
  for (int j = 0; j < 4; ++j) { ua[j] = f2bf(va[j]); ub[j] = f2bf(vb[j]); }
  ((u16x4*)oa)[i] = ua;
  ((u16x4*)ob)[i] = ub;
}

// ---------------------------------------------------------------------------
// z<8: W [K=1024][1024] f32 -> Wt [1024][1024] bf16 into WTall slot z.
// z==8: gate W [2048][1024] -> WgT [1024][2048].
// z==9,10: plain (no transpose) f32->bf16 of Wo into WoBF slot z-9.
struct Src11 { const float* p[11]; };

__global__ __launch_bounds__(256) void transpose_cvt(
    Src11 srcs, ushort_t* __restrict__ WTall, ushort_t* __restrict__ WgT,
    ushort_t* __restrict__ WoBF) {
  const int z = blockIdx.z;
  if (z != 8 && blockIdx.y >= 32) return;
  const float* src = srcs.p[z];
  int tx = threadIdx.x & 31, ty = threadIdx.x >> 5;
  int n0 = blockIdx.x << 5, k0 = blockIdx.y << 5;
  if (z >= 9) {
    ushort_t* dst = WoBF + ((size_t)(z - 9) << 20);
#pragma unroll
    for (int i = 0; i < 4; ++i) {
      size_t off = (size_t)(k0 + ty + i * 8) * 1024 + n0 + tx;
      dst[off] = f2bf(src[off]);
    }
    return;
  }
  const int K = (z == 8) ? 2048 : 1024;
  ushort_t* dst = (z == 8) ? WgT : WTall + ((size_t)z << 20);
  __shared__ float t[32][33];
#pragma unroll
  for (int i = 0; i < 4; ++i)
    t[ty + i * 8][tx] = src[(size_t)(k0 + ty + i * 8) * 1024 + n0 + tx];
  __syncthreads();
#pragma unroll
  for (int i = 0; i < 4; ++i)
    dst[(size_t)(n0 + ty + i * 8) * K + k0 + tx] = f2bf(t[tx][ty + i * 8]);
}

// ---------------------------------------------------------------------------
// gb2[dir][n] = sum_k bo_dir[k] * Wg[1024+k][n]  (= bo @ Wg_bot).
__global__ __launch_bounds__(256) void gb2_kernel(
    const float* __restrict__ bo0, const float* __restrict__ bo1,
    const ushort_t* __restrict__ WgT, float* __restrict__ gb2) {
  const int wgl = blockIdx.x * 4 + (threadIdx.x >> 6);  // 0..2047
  const int lane = threadIdx.x & 63;
  const int dir = wgl >> 10, n = wgl & 1023;
  const float* bo = dir ? bo1 : bo0;
  const ushort_t* wrow = WgT + ((size_t)n << 11) + 1024 + (lane << 4);
  float s = 0.f;
#pragma unroll
  for (int j = 0; j < 16; ++j) s += bo[(lane << 4) + j] * bf2f(wrow[j]);
#pragma unroll
  for (int d = 1; d < 64; d <<= 1) s += __shfl_xor(s, d, 64);
  if (lane == 0) gb2[wgl] = s;
}

// ---------------------------------------------------------------------------
// WpT[g][n][j] = sum_k Wo_g[j][k] * Wg[1024+k][n]   (= (Wo_g @ Wg_bot)^T)
__global__ __launch_bounds__(256, 3) void gemm_wp(
    const ushort_t* __restrict__ WgT, const ushort_t* __restrict__ WoBF,
    ushort_t* __restrict__ WpT) {
  __shared__ ushort_t As[128 * 64];
  __shared__ ushort_t Bs[128 * 64];
  const int tid = threadIdx.x;
  const int w = tid >> 6, lane = tid & 63;
  const int g = lane >> 4, c = lane & 15;
  const int wm = (w >> 1) << 6, wn = (w & 1) << 6;
  const int m0 = blockIdx.x << 7, n0 = blockIdx.y << 7;
  const int group = m0 >> 10;
  const int csw = (lane & 7) ^ (lane >> 3);

  f32x4 acc[4][4];
#pragma unroll
  for (int i = 0; i < 4; ++i)
#pragma unroll
    for (int j = 0; j < 4; ++j) acc[i][j] = f32x4{0.f, 0.f, 0.f, 0.f};

  for (int k0 = 0; k0 < 1024; k0 += 64) {
#pragma unroll
    for (int i = 0; i < 4; ++i) {
      const int chunk = (w << 2) + i;
      const int row = (chunk << 3) + (lane >> 3);
      gload16(WgT + ((size_t)((m0 + row) & 1023) << 11) + 1024 + k0 + (csw << 3),
              &As[(size_t)chunk << 9]);
      gload16(WoBF + ((size_t)group << 20) + ((size_t)(n0 + row) << 10) + k0 + (csw << 3),
              &Bs[(size_t)chunk << 9]);
    }
    __syncthreads();
    const int cg = c & 7;
#pragma unroll
    for (int ks = 0; ks < 2; ++ks) {
      bf16x8 af[4], bfr[4];
#pragma unroll
      for (int mi = 0; mi < 4; ++mi)
        af[mi] = *(const bf16x8*)&As[((wm + mi * 16 + c) << 6) +
                                     ((((ks << 2) | g) ^ cg) << 3)];
#pragma unroll
      for (int ni = 0; ni < 4; ++ni)
        bfr[ni] = *(const bf16x8*)&Bs[((wn + ni * 16 + c) << 6) +
                                      ((((ks << 2) | g) ^ cg) << 3)];
#pragma unroll
      for (int mi = 0; mi < 4; ++mi)
#pragma unroll
        for (int ni = 0; ni < 4; ++ni)
          acc[mi][ni] = __builtin_amdgcn_mfma_f32_16x16x32_bf16(
              af[mi], bfr[ni], acc[mi][ni], 0, 0, 0);
    }
    __syncthreads();
  }
#pragma unroll
  for (int ni = 0; ni < 4; ++ni) {
    const int n = n0 + wn + ni * 16 + c;
#pragma unroll
    for (int mi = 0; mi < 4; ++mi) {
      const int mb = m0 + wm + mi * 16 + (g << 2);
      f32x4 a = acc[mi][ni];
#pragma unroll
      for (int r = 0; r < 4; ++r)
        WpT[((size_t)group << 20) + ((size_t)((mb + r) & 1023) << 10) + n] = f2bf(a[r]);
    }
  }
}

// ---------------------------------------------------------------------------
// 128x128 / BK=64 / 4-wave GEMM (proven engine, unchanged from r5).
enum { M_QKVG = 0, M_OG = 1 };
struct Bias8 { const float* p[8]; };

template <int MODE>
__global__ __launch_bounds__(256, 3) void gemm_kernel(
    const ushort_t* __restrict__ Aa, const ushort_t* __restrict__ Ab,
    const ushort_t* __restrict__ WTall, const ushort_t* __restrict__ WgT,
    const ushort_t* __restrict__ WpT, Bias8 bt, const float* __restrict__ gb2,
    ushort_t* __restrict__ outQ, ushort_t* __restrict__ gt) {
  __shared__ ushort_t As[128 * 64];
  __shared__ ushort_t Bs[128 * 64];
  const int tid = threadIdx.x;
  const int w = tid >> 6, lane = tid & 63;
  const int g = lane >> 4, c = lane & 15;
  const int wm = (w >> 1) << 6, wn = (w & 1) << 6;
  const int bid = (int)blockIdx.x;
  const int xcd = bid & 7, idx = bid >> 3;
  const int mt = (xcd << 3) + (idx & 7), nt = idx >> 3;
  const int m0 = mt << 7, n0 = nt << 7;
  const int group = m0 >> 12;
  const int nch = n0 >> 10;
  const int csw = (lane & 7) ^ (lane >> 3);

  const ushort_t* Asrc = (MODE == M_QKVG)
      ? ((group ? Ab : Aa) + ((size_t)(m0 & 4095) << 10))
      : (Aa + ((size_t)m0 << 10));

  const ushort_t* Bb;
  int bstr, bidx = -1;
  if (MODE == M_QKVG) {
    if (nch < 3) {
      bidx = group * 3 + nch;
      Bb = WTall + ((size_t)bidx << 20) + ((size_t)(n0 & 1023) << 10);
      bstr = 1024;
    } else {
      Bb = WgT + ((size_t)(n0 & 1023) << 11);
      bstr = 2048;
    }
  } else {
    if (nch == 0) {
      Bb = WTall + ((size_t)(6 + group) << 20) + ((size_t)n0 << 10);
      bstr = 1024;
    } else {
      Bb = WpT + ((size_t)group << 20) + ((size_t)(n0 & 1023) << 10);
      bstr = 1024;
    }
  }

  f32x4 acc[4][4];
#pragma unroll
  for (int i = 0; i < 4; ++i)
#pragma unroll
    for (int j = 0; j < 4; ++j) acc[i][j] = f32x4{0.f, 0.f, 0.f, 0.f};

  for (int k0 = 0; k0 < 1024; k0 += 64) {
#pragma unroll
    for (int i = 0; i < 4; ++i) {
      const int chunk = (w << 2) + i;
      const int row = (chunk << 3) + (lane >> 3);
      gload16(Asrc + ((size_t)row << 10) + k0 + (csw << 3), &As[(size_t)chunk << 9]);
      gload16(Bb + (size_t)row * bstr + k0 + (csw << 3), &Bs[(size_t)chunk << 9]);
    }
    __syncthreads();
    const int cg = c & 7;
#pragma unroll
    for (int ks = 0; ks < 2; ++ks) {
      bf16x8 af[4], bfr[4];
#pragma unroll
      for (int mi = 0; mi < 4; ++mi)
        af[mi] = *(const bf16x8*)&As[((wm + mi * 16 + c) << 6) +
                                     ((((ks << 2) | g) ^ cg) << 3)];
#pragma unroll
      for (int ni = 0; ni < 4; ++ni)
        bfr[ni] = *(const bf16x8*)&Bs[((wn + ni * 16 + c) << 6) +
                                      ((((ks << 2) | g) ^ cg) << 3)];
#pragma unroll
      for (int mi = 0; mi < 4; ++mi)
#pragma unroll
        for (int ni = 0; ni < 4; ++ni)
          acc[mi][ni] = __builtin_amdgcn_mfma_f32_16x16x32_bf16(
              af[mi], bfr[ni], acc[mi][ni], 0, 0, 0);
    }
    __syncthreads();
  }

  // Epilogue. D frag: row(M) = 4*(lane>>4)+reg, col(N) = lane&15.
#pragma unroll
  for (int ni = 0; ni < 4; ++ni) {
    const int n = n0 + wn + ni * 16 + c;
    const int nloc = n & 1023;
    float bv;
    if (MODE == M_QKVG)
      bv = (nch < 3) ? bt.p[bidx][nloc]
                     : bt.p[6][nloc] + gb2[(group << 10) + nloc];
    else
      bv = (nch == 0) ? bt.p[group][nloc] : 0.f;
#pragma unroll
    for (int mi = 0; mi < 4; ++mi) {
      const int mb = m0 + wm + mi * 16 + (g << 2);
      f32x4 a = acc[mi][ni];
      if (MODE == M_QKVG) {
        if (nch < 3) {
          const int mrow = mb & 4095, b = mrow >> 9, s = mrow & 511;
          const int h = nloc >> 6, d = nloc & 63;
          ushort_t* base = outQ + ((size_t)bidx << 22);
          if (bidx == 1 || bidx == 5) {  // V^T [b][h][d][s]
            u16x4 o;
#pragma unroll
            for (int r = 0; r < 4; ++r) o[r] = f2bf(a[r] + bv);
            *(u16x4*)&base[(((size_t)((b * 16 + h) * 64 + d)) << 9) + s] = o;
          } else {  // [b][h][s][d]
#pragma unroll
            for (int r = 0; r < 4; ++r)
              base[(((size_t)((b * 16 + h) * 512 + s + r)) << 6) + d] = f2bf(a[r] + bv);
          }
        } else {  // gt = X @ Wg_top + gate_b + gb2
#pragma unroll
          for (int r = 0; r < 4; ++r)
            gt[((size_t)(mb + r) << 10) + nloc] = f2bf(a[r] + bv);
        }
      } else {
        if (nch == 0) {  // ao = ctx @ Wo + bo
#pragma unroll
          for (int r = 0; r < 4; ++r)
            outQ[((size_t)(mb + r) << 10) + nloc] = f2bf(a[r] + bv);
        } else {  // gpart = ctx @ W'
#pragma unroll
          for (int r = 0; r < 4; ++r)
            gt[((size_t)(mb + r) << 10) + nloc] = f2bf(a[r]);
        }
      }
    }
  }
}

// ---------------------------------------------------------------------------
// Flash-style fused attention, both dirs. 2048 blocks (XCD-swizzled), 4 waves,
// wave owns 16 q rows. 8 chunks of 64 k-rows with online softmax; K and V
// double-buffered in 4x8KB LDS (global_load_lds + XOR swizzle). Register state
// per lane: st[4] chunk scores + running (m,sum) + pacc -> 4 blocks/CU.
// KL row-shift dropped (softmax shift-invariant). scores^T = mfma(K,Q).
__global__ __launch_bounds__(256, 4) void attn_kernel(
    const ushort_t* __restrict__ QKV, ushort_t* __restrict__ ctx) {
  __shared__ ushort_t Ks[2][4096];
  __shared__ ushort_t Vs[2][4096];
  const int tid = threadIdx.x, w = tid >> 6, lane = tid & 63;
  const int g = lane >> 4, c = lane & 15, c7 = c & 7;
  const int bid = (int)blockIdx.x;
  const int wid = (bid & 7) * 256 + (bid >> 3);  // XCD-contiguous work ids
  const int dir = wid >> 10;
  const int bh = (wid >> 3) & 127, qt = wid & 7;
  const int q0 = (qt << 6) + (w << 4);
  const int qs = dir ? 2 : 3, ks = dir ? 4 : 0, vs = dir ? 5 : 1;
  const ushort_t* Qb = QKV + ((size_t)qs << 22) + ((size_t)bh << 15);
  const ushort_t* Kb = QKV + ((size_t)ks << 22) + ((size_t)bh << 15);
  const ushort_t* Vb = QKV + ((size_t)vs << 22) + ((size_t)bh << 15);  // [64][512]

  // K chunk cc: rows cc*64..+63 (k), 64 d-cols. 8 KB, 2 loads/thread.
  auto stageK = [&](int b, int kc) {
#pragma unroll
    for (int i = 0; i < 2; ++i) {
      int idx = tid + (i << 8);
      int r = idx >> 3, sl = idx & 7;
      int cs = sl ^ (r & 7);
      gload16(Kb + (((size_t)((kc << 6) + r)) << 6) + (cs << 3), &Ks[b][idx << 3]);
    }
  };
  // V chunk cc: 64 d-rows, s-cols cc*64..+63 from V^T [64][512]. 8 KB.
  auto stageV = [&](int b, int vc) {
#pragma unroll
    for (int i = 0; i < 2; ++i) {
      int idx = tid + (i << 8);
      int r = idx >> 3, sl = idx & 7;
      int cs = sl ^ (r & 7);
      gload16(Vb + ((size_t)r << 9) + (vc << 6) + (cs << 3), &Vs[b][idx << 3]);
    }
  };

  bf16x8 qf0 = *(const bf16x8*)&Qb[((q0 + c) << 6) + (g << 3)];
  bf16x8 qf1 = *(const bf16x8*)&Qb[((q0 + c) << 6) + 32 + (g << 3)];

  const float SC = 0.125f;  // 1/sqrt(64)
  float m = -1e30f, sum = 0.f;
  f32x4 pacc[4];
#pragma unroll
  for (int dt = 0; dt < 4; ++dt) pacc[dt] = f32x4{0.f, 0.f, 0.f, 0.f};
  const int s1 = ((g & 1) << 5) + c;  // repack source lanes
  const int s2 = s1 + 16;
  const bool hi = (g >> 1) != 0;

  stageK(0, 0);
  stageV(0, 0);
  __syncthreads();

#pragma unroll
  for (int cc = 0; cc < 8; ++cc) {
    const int buf = cc & 1;
    if (cc < 7) { stageK(buf ^ 1, cc + 1); stageV(buf ^ 1, cc + 1); }

    // QK^T for this chunk: 4 tiles of 16 k-rows. st[t] rows = 16t+4g+reg.
    f32x4 st[4];
    __builtin_amdgcn_s_setprio(1);
#pragma unroll
    for (int t = 0; t < 4; ++t) {
      const ushort_t* base = &Ks[buf][((t << 4) + c) << 6];
      bf16x8 a0 = *(const bf16x8*)&base[(g ^ c7) << 3];
      bf16x8 a1 = *(const bf16x8*)&base[((4 | g) ^ c7) << 3];
      f32x4 z = {0.f, 0.f, 0.f, 0.f};
      z = __builtin_amdgcn_mfma_f32_16x16x32_bf16(a0, qf0, z, 0, 0, 0);
      z = __builtin_amdgcn_mfma_f32_16x16x32_bf16(a1, qf1, z, 0, 0, 0);
      st[t] = z;
    }
    __builtin_amdgcn_s_setprio(0);

    // online softmax: chunk max (cross-g reduce), rescale running state
    float mx = fmaxf(fmaxf(st[0][0], st[0][1]), fmaxf(st[0][2], st[0][3]));
#pragma unroll
    for (int t = 1; t < 4; ++t)
      mx = fmaxf(mx, fmaxf(fmaxf(st[t][0], st[t][1]), fmaxf(st[t][2], st[t][3])));
    mx = fmaxf(mx, __shfl_xor(mx, 16, 64));
    mx = fmaxf(mx, __shfl_xor(mx, 32, 64));
    const float mn = fmaxf(m, mx);
    const float scale = __expf((m - mn) * SC);
    m = mn;
    float ls = 0.f;
#pragma unroll
    for (int t = 0; t < 4; ++t)
#pragma unroll
      for (int r = 0; r < 4; ++r) {
        float p = __expf((st[t][r] - mn) * SC);
        st[t][r] = p;
        ls += p;
      }
    ls += __shfl_xor(ls, 16, 64);
    ls += __shfl_xor(ls, 32, 64);
    sum = sum * scale + ls;
#pragma unroll
    for (int dt = 0; dt < 4; ++dt)
#pragma unroll
      for (int r = 0; r < 4; ++r) pacc[dt][r] *= scale;

    // PV for this chunk: 2 k-units of 32, repack P via shuffles, 8 MFMA
#pragma unroll
    for (int u = 0; u < 2; ++u) {
      u32 A0 = ((u32)f2bf(st[2 * u][1]) << 16) | f2bf(st[2 * u][0]);
      u32 A1p = ((u32)f2bf(st[2 * u][3]) << 16) | f2bf(st[2 * u][2]);
      u32 B0 = ((u32)f2bf(st[2 * u + 1][1]) << 16) | f2bf(st[2 * u + 1][0]);
      u32 B1 = ((u32)f2bf(st[2 * u + 1][3]) << 16) | f2bf(st[2 * u + 1][2]);
      u32 xA0 = (u32)__shfl((int)A0, s1, 64), xA1 = (u32)__shfl((int)A1p, s1, 64);
      u32 xB0 = (u32)__shfl((int)B0, s1, 64), xB1 = (u32)__shfl((int)B1, s1, 64);
      u32 yA0 = (u32)__shfl((int)A0, s2, 64), yA1 = (u32)__shfl((int)A1p, s2, 64);
      u32 yB0 = (u32)__shfl((int)B0, s2, 64), yB1 = (u32)__shfl((int)B1, s2, 64);
      union { bf16x8 v; u32 wd[4]; } pb;
      pb.wd[0] = hi ? xB0 : xA0;
      pb.wd[1] = hi ? xB1 : xA1;
      pb.wd[2] = hi ? yB0 : yA0;
      pb.wd[3] = hi ? yB1 : yA1;
      __builtin_amdgcn_s_setprio(1);
#pragma unroll
      for (int dt = 0; dt < 4; ++dt) {
        bf16x8 av = *(const bf16x8*)
            &Vs[buf][(((dt << 4) + c) << 6) + ((((u << 2) | g) ^ c7) << 3)];
        pacc[dt] = __builtin_amdgcn_mfma_f32_16x16x32_bf16(av, pb.v, pacc[dt], 0, 0, 0);
      }
      __builtin_amdgcn_s_setprio(0);
    }
    __syncthreads();
  }

  const float inv = 1.0f / sum;
  const int b = bh >> 4, h = bh & 15;
  size_t obase = ((size_t)dir << 22) + ((size_t)(b * 512 + q0 + c) << 10) + (h << 6);
#pragma unroll
  for (int dt = 0; dt < 4; ++dt) {
    u16x4 o;
#pragma unroll
    for (int r = 0; r < 4; ++r) o[r] = f2bf(pacc[dt][r] * inv);
    *(u16x4*)&ctx[obase + (dt << 4) + (g << 2)] = o;
  }
}

// ---------------------------------------------------------------------------
// gate = sigmoid(gt + gpart); f = gate*x + (1-gate)*ao; out = LayerNorm(f)
__global__ __launch_bounds__(256) void fuse_ln(
    const float* __restrict__ xt, const float* __restrict__ xc,
    const ushort_t* __restrict__ ao, const ushort_t* __restrict__ gt,
    const ushort_t* __restrict__ gp,
    const float* __restrict__ lng, const float* __restrict__ lnb,
    float* __restrict__ out) {
  const int row = blockIdx.x, dir = row >> 12, r = row & 4095;
  const float* x = (dir ? xc : xt) + ((size_t)r << 10);
  const ushort_t* a = ao + ((size_t)row << 10);
  const ushort_t* g1 = gt + ((size_t)row << 10);
  const ushort_t* g2 = gp + ((size_t)row << 10);
  float* o = out + ((size_t)row << 10);
  const int t = threadIdx.x, w = t >> 6, lane = t & 63;
  f32x4 xv = ((const f32x4*)x)[t];
  u16x4 av = ((const u16x4*)a)[t];
  u16x4 gv = ((const u16x4*)g1)[t];
  u16x4 pv = ((const u16x4*)g2)[t];
  f32x4 f;
  float sm = 0.f, sq = 0.f;
#pragma unroll
  for (int j = 0; j < 4; ++j) {
    float gate = 1.f / (1.f + __expf(-(bf2f(gv[j]) + bf2f(pv[j]))));
    float fv = gate * xv[j] + (1.f - gate) * bf2f(av[j]);
    f[j] = fv; sm += fv; sq += fv * fv;
  }
#pragma unroll
  for (int d = 1; d < 64; d <<= 1) {
    sm += __shfl_xor(sm, d, 64);
    sq += __shfl_xor(sq, d, 64);
  }
  __shared__ float ps[8];
  if (lane == 0) { ps[w] = sm; ps[4 + w] = sq; }
  __syncthreads();
  sm = ps[0] + ps[1] + ps[2] + ps[3];
  sq = ps[4] + ps[5] + ps[6] + ps[7];
  const float mu = sm * (1.f / 1024.f);
  const float var = sq * (1.f / 1024.f) - mu * mu;
  const float rstd = rsqrtf(var + 1e-5f);
  f32x4 lg = ((const f32x4*)lng)[t], lb = ((const f32x4*)lnb)[t];
  f32x4 ov;
#pragma unroll
  for (int j = 0; j < 4; ++j) ov[j] = lg[j] * (f[j] - mu) * rstd + lb[j];
  ((f32x4*)o)[t] = ov;
}

// ---------------------------------------------------------------------------
extern "C" void kernel_launch(void* const* d_in, const int* in_sizes, int n_in,
                              void* d_out, int out_size, void* d_ws, size_t ws_size,
                              hipStream_t stream) {
  (void)in_sizes; (void)n_in; (void)out_size; (void)ws_size;
  const float* title = (const float*)d_in[0];
  const float* content = (const float*)d_in[1];

  char* ws = (char*)d_ws;
  const size_t MB = 1u << 20;
  ushort_t* Xt    = (ushort_t*)(ws + 0 * MB);    // 8 MB bf16 [4096][1024]
  ushort_t* Xc    = (ushort_t*)(ws + 8 * MB);    // 8 MB
  ushort_t* ctx   = (ushort_t*)(ws + 0 * MB);    // 16 MB (X dead after QKVG)
  ushort_t* WTall = (ushort_t*)(ws + 16 * MB);   // 16 MB: 8 slots [1024][1024]
  ushort_t* WgT   = (ushort_t*)(ws + 32 * MB);   // 4 MB [1024][2048]
  ushort_t* QKV   = (ushort_t*)(ws + 36 * MB);   // 48 MB: 6 slots of 8 MB
  ushort_t* ao    = (ushort_t*)(ws + 36 * MB);   // 16 MB (QKV slots 0-1, dead post-attn)
  ushort_t* gpart = (ushort_t*)(ws + 52 * MB);   // 16 MB (QKV slots 2-3, dead post-attn)
  ushort_t* gt    = (ushort_t*)(ws + 84 * MB);   // 16 MB bf16 [8192][1024]
  ushort_t* WoBF  = (ushort_t*)(ws + 100 * MB);  // 4 MB: 2 slots [1024][1024]
  ushort_t* WpT   = (ushort_t*)(ws + 104 * MB);  // 4 MB: 2 slots [1024][1024]
  float*    gb2   = (float*)   (ws + 108 * MB);  // 8 KB [2][1024]

  cvt_inputs<<<4096, 256, 0, stream>>>(title, content, Xt, Xc);

  // slots: {t2c_wk,t2c_wv,c2t_wq, t2c_wq,c2t_wk,c2t_wv, t2c_wo,c2t_wo}, gate, Wo x2
  Src11 srcs;
  srcs.p[0] = (const float*)d_in[4];  srcs.p[1] = (const float*)d_in[6];
  srcs.p[2] = (const float*)d_in[10]; srcs.p[3] = (const float*)d_in[2];
  srcs.p[4] = (const float*)d_in[12]; srcs.p[5] = (const float*)d_in[14];
  srcs.p[6] = (const float*)d_in[8];  srcs.p[7] = (const float*)d_in[16];
  srcs.p[8] = (const float*)d_in[18];
  srcs.p[9] = (const float*)d_in[8];  srcs.p[10] = (const float*)d_in[16];
  transpose_cvt<<<dim3(32, 64, 11), 256, 0, stream>>>(srcs, WTall, WgT, WoBF);

  gb2_kernel<<<512, 256, 0, stream>>>((const float*)d_in[9], (const float*)d_in[17],
                                      WgT, gb2);
  gemm_wp<<<dim3(16, 8), 256, 0, stream>>>(WgT, WoBF, WpT);

  Bias8 bq;
  bq.p[0] = (const float*)d_in[5];  bq.p[1] = (const float*)d_in[7];
  bq.p[2] = (const float*)d_in[11]; bq.p[3] = (const float*)d_in[3];
  bq.p[4] = (const float*)d_in[13]; bq.p[5] = (const float*)d_in[15];
  bq.p[6] = (const float*)d_in[19]; bq.p[7] = nullptr;
  gemm_kernel<M_QKVG><<<2048, 256, 0, stream>>>(Xt, Xc, WTall, WgT, WpT, bq, gb2,
                                                QKV, gt);

  attn_kernel<<<2048, 256, 0, stream>>>(QKV, ctx);

  Bias8 bo;
  bo.p[0] = (const float*)d_in[9]; bo.p[1] = (const float*)d_in[17];
  for (int i = 2; i < 8; ++i) bo.p[i] = nullptr;
  gemm_kernel<M_OG><<<1024, 256, 0, stream>>>(ctx, nullptr, WTall, WgT, WpT, bo, gb2,
                                              ao, gpart);

  fuse_ln<<<8192, 256, 0, stream>>>(title, content, ao, gt, gpart,
                                    (const float*)d_in[20], (const float*)d_in[21],
                                    (float*)d_out);
}